// Round 7
// baseline (769.277 us; speedup 1.0000x reference)
//
#include <hip/hip_runtime.h>
#include <hip/hip_bf16.h>

#define H 128

typedef _Float16 f16x4 __attribute__((ext_vector_type(4)));
typedef _Float16 f16x8 __attribute__((ext_vector_type(8)));
typedef float    f32x4 __attribute__((ext_vector_type(4)));
typedef float    f32x2 __attribute__((ext_vector_type(2)));

__device__ __forceinline__ float silu_f(float v) {
    return v / (1.0f + __expf(-v));
}

// ---------------------------------------------------------------------------
// prep_k: hist (all 2500 blocks) + weight pre-pack (blocks 0..79).
// cnt must be pre-zeroed (memset on stream).
// ---------------------------------------------------------------------------
__global__ __launch_bounds__(256)
void prep_k(const int* __restrict__ eidx, int* __restrict__ cnt,
            const float* __restrict__ emb_w, const float* __restrict__ conv_w,
            const float* __restrict__ out_w, _Float16* __restrict__ wpk)
{
    const int e = blockIdx.x * 256 + threadIdx.x;       // 640000 exact
    const int row = eidx[2 * (size_t)e];
    const int b = (unsigned)e / 160000u;
    atomicAdd(&cnt[b * 10000 + row], 1);

    if (blockIdx.x < 80) {
        const int gid = blockIdx.x * 256 + threadIdx.x; // 20480 = 10*2048
        const int mat = gid >> 11;
        const int r   = gid & 2047;
        const int ct  = r >> 8;
        const int kb  = (r >> 6) & 3;
        const int lane = r & 63;
        const float* W = (mat < 4) ? emb_w + mat * 16384
                       : (mat < 8) ? conv_w + (mat - 4) * 16384
                                   : out_w + (mat - 8) * 16384;
        const int m  = ct * 16 + (lane & 15);
        const int k0 = kb * 32 + (lane >> 4) * 8;
        _Float16* dst = wpk + (size_t)gid * 8;
#pragma unroll
        for (int j = 0; j < 8; ++j)
            dst[j] = (_Float16)W[(k0 + j) * H + m];
    }
}

// ---------------------------------------------------------------------------
// MFMA helpers. CT = 16-col tiles per wave, ct0 = wave's first tile.
// ---------------------------------------------------------------------------
template <int CT>
__device__ __forceinline__ void mfma_layerT(const _Float16* __restrict__ w,
                                            const f16x8 bf[4], int ct0, int lane,
                                            f32x4 acc[CT])
{
#pragma unroll
    for (int c = 0; c < CT; ++c) acc[c] = (f32x4){0.f, 0.f, 0.f, 0.f};
#pragma unroll
    for (int kb = 0; kb < 4; ++kb) {
#pragma unroll
        for (int ctl = 0; ctl < CT; ++ctl) {
            f16x8 af = *(const f16x8*)(w + ((size_t)((ct0 + ctl) * 4 + kb) * 64 + lane) * 8);
            acc[ctl] = __builtin_amdgcn_mfma_f32_16x16x32_f16(af, bf[kb], acc[ctl], 0, 0, 0);
        }
    }
}

template <int CT>
__device__ __forceinline__ void store_stripT(_Float16* strip, const f32x4 acc[CT],
                                             const float* bias, int ct0, int rl, int quad)
{
#pragma unroll
    for (int ctl = 0; ctl < CT; ++ctl) {
        const int c = (ct0 + ctl) * 16 + quad * 4;
        float4 bb = *(const float4*)(bias + c);
        f16x4 hv = {(_Float16)silu_f(acc[ctl][0] + bb.x),
                    (_Float16)silu_f(acc[ctl][1] + bb.y),
                    (_Float16)silu_f(acc[ctl][2] + bb.z),
                    (_Float16)silu_f(acc[ctl][3] + bb.w)};
        *(f16x4*)(strip + rl * 136 + c) = hv;
    }
}

template <int CT>
__device__ __forceinline__ void store_strip_rawT(_Float16* strip, const f32x4 t[CT],
                                                 int ct0, int rl, int quad)
{
#pragma unroll
    for (int ctl = 0; ctl < CT; ++ctl) {
        const int c = (ct0 + ctl) * 16 + quad * 4;
        f16x4 hv = {(_Float16)t[ctl][0], (_Float16)t[ctl][1],
                    (_Float16)t[ctl][2], (_Float16)t[ctl][3]};
        *(f16x4*)(strip + rl * 136 + c) = hv;
    }
}

__device__ __forceinline__ void load_bf(const _Float16* strip, f16x8 bf[4],
                                        int rl, int quad)
{
#pragma unroll
    for (int kb = 0; kb < 4; ++kb)
        bf[kb] = *(const f16x8*)(strip + rl * 136 + kb * 32 + quad * 8);
}

// ---------------------------------------------------------------------------
// scat_emb_k: blocks 0..2499 = scatter (sort pass 2); blocks 2500..4999 =
// emb2 (s2s = mlp2(x; mats 0,1), sdst = mlp2(x; mats 2,3)).
// ---------------------------------------------------------------------------
__global__ __launch_bounds__(256)
void scat_emb_k(const int* __restrict__ eidx, int* __restrict__ cursor,
                int2* __restrict__ meta,
                const float* __restrict__ x, const _Float16* __restrict__ wpk,
                const float* __restrict__ emb_b,
                float* __restrict__ s2s, float* __restrict__ sdst)
{
    __shared__ _Float16 hsA[16 * 136], hsB[16 * 136];
    if (blockIdx.x < 2500) {
        const int e = blockIdx.x * 256 + threadIdx.x;   // 640000 exact
        const int2 rc = ((const int2*)eidx)[e];
        const int b = (unsigned)e / 160000u;
        const int pos = atomicAdd(&cursor[b * 10000 + rc.x], 1);
        meta[pos] = make_int2(e, b * 10000 + rc.y);
        return;
    }

    const int bid  = blockIdx.x - 2500;
    const int tid  = threadIdx.x;
    const int lane = tid & 63;
    const int wid  = tid >> 6;
    const int half = wid & 1;
    const int msel = wid >> 1;
    const int rl   = lane & 15;
    const int quad = lane >> 4;
    const int row  = bid * 16 + rl;
    const size_t rbase = (size_t)row * H;

    f16x8 bf[4];
#pragma unroll
    for (int kb = 0; kb < 4; ++kb) {
        const int kc = kb * 32 + quad * 8;
        float4 v0 = *(const float4*)(x + rbase + kc);
        float4 v1 = *(const float4*)(x + rbase + kc + 4);
        bf[kb] = (f16x8){(_Float16)v0.x, (_Float16)v0.y, (_Float16)v0.z, (_Float16)v0.w,
                         (_Float16)v1.x, (_Float16)v1.y, (_Float16)v1.z, (_Float16)v1.w};
    }

    const _Float16* wm = wpk + (size_t)msel * 2 * 16384;
    _Float16* strip = msel ? hsB : hsA;
    const float* bias0 = emb_b + msel * 2 * H;

    f32x4 acc[4];
    mfma_layerT<4>(wm, bf, half * 4, lane, acc);
    store_stripT<4>(strip, acc, bias0, half * 4, rl, quad);
    __syncthreads();
    load_bf(strip, bf, rl, quad);
    mfma_layerT<4>(wm + 16384, bf, half * 4, lane, acc);

    float* outp = msel ? sdst : s2s;
    const float* bias1 = bias0 + H;
#pragma unroll
    for (int ctl = 0; ctl < 4; ++ctl) {
        const int c = (half * 4 + ctl) * 16 + quad * 4;
        float4 bb = *(const float4*)(bias1 + c);
        float4 v;
        v.x = silu_f(acc[ctl][0] + bb.x);
        v.y = silu_f(acc[ctl][1] + bb.y);
        v.z = silu_f(acc[ctl][2] + bb.z);
        v.w = silu_f(acc[ctl][3] + bb.w);
        *(float4*)(outp + rbase + c) = v;
    }
}

// ---------------------------------------------------------------------------
// Single-block exclusive scan of 40960 counters (1024 threads x 40 elements).
// ---------------------------------------------------------------------------
__global__ __launch_bounds__(1024)
void scan_k(const int* __restrict__ cnt, int* __restrict__ offs,
            int* __restrict__ cursor)
{
    __shared__ int sh[1024];
    const int t = threadIdx.x;
    const int base = t * 40;
    int vals[40];
    int s = 0;
#pragma unroll
    for (int i = 0; i < 40; ++i) { vals[i] = cnt[base + i]; s += vals[i]; }
    sh[t] = s;
    __syncthreads();
    for (int off = 1; off < 1024; off <<= 1) {
        int v = (t >= off) ? sh[t - off] : 0;
        __syncthreads();
        sh[t] += v;
        __syncthreads();
    }
    int run = (t > 0) ? sh[t - 1] : 0;
#pragma unroll
    for (int i = 0; i < 40; ++i) {
        offs[base + i] = run;
        cursor[base + i] = run;
        run += vals[i];
    }
    if (t == 1023) offs[40960] = run;
}

// ---------------------------------------------------------------------------
// out6_k: fused tail — conv -> residual(conv_w0) -> residual(conv_w1)
//                      -> z = s2s .* conv -> out = z + mlp2(z; out_w)
// 256-thread block = 4 waves, each owns 32 out-cols.  Residual/mul operands
// prefetched at entry so mid-chain loads don't add exposed latency.
// ---------------------------------------------------------------------------
__global__ __launch_bounds__(256)
void out6_k(const float* __restrict__ conv, const float* __restrict__ s2s,
            const _Float16* __restrict__ w6,
            const float* __restrict__ conv_b, const float* __restrict__ out_b,
            float* __restrict__ y)
{
    __shared__ _Float16 hs0[16 * 136], hs1[16 * 136];
    const int tid  = threadIdx.x;
    const int lane = tid & 63;
    const int ct0  = (tid >> 6) * 2;
    const int rl   = lane & 15;
    const int quad = lane >> 4;
    const int row  = blockIdx.x * 16 + rl;
    const size_t rbase = (size_t)row * H;

    f16x8 bf[4];
#pragma unroll
    for (int kb = 0; kb < 4; ++kb) {
        const int kc = kb * 32 + quad * 8;
        float4 v0 = *(const float4*)(conv + rbase + kc);
        float4 v1 = *(const float4*)(conv + rbase + kc + 4);
        bf[kb] = (f16x8){(_Float16)v0.x, (_Float16)v0.y, (_Float16)v0.z, (_Float16)v0.w,
                         (_Float16)v1.x, (_Float16)v1.y, (_Float16)v1.z, (_Float16)v1.w};
    }
    // prefetch residual (conv) and mul (s2s) operands in D-layout positions
    float4 cvr[2], svr[2];
#pragma unroll
    for (int ctl = 0; ctl < 2; ++ctl) {
        const int c = (ct0 + ctl) * 16 + quad * 4;
        cvr[ctl] = *(const float4*)(conv + rbase + c);
        svr[ctl] = *(const float4*)(s2s + rbase + c);
    }

    f32x4 acc[2], tD[2];

    // L0: hidden of residual-1
    mfma_layerT<2>(w6, bf, ct0, lane, acc);
    store_stripT<2>(hs0, acc, conv_b, ct0, rl, quad);
    __syncthreads();
    load_bf(hs0, bf, rl, quad);

    // L1: t = conv + mlp_out
    mfma_layerT<2>(w6 + 16384, bf, ct0, lane, acc);
#pragma unroll
    for (int ctl = 0; ctl < 2; ++ctl) {
        const int c = (ct0 + ctl) * 16 + quad * 4;
        float4 bb = *(const float4*)(conv_b + H + c);
        tD[ctl][0] = cvr[ctl].x + silu_f(acc[ctl][0] + bb.x);
        tD[ctl][1] = cvr[ctl].y + silu_f(acc[ctl][1] + bb.y);
        tD[ctl][2] = cvr[ctl].z + silu_f(acc[ctl][2] + bb.z);
        tD[ctl][3] = cvr[ctl].w + silu_f(acc[ctl][3] + bb.w);
    }
    store_strip_rawT<2>(hs1, tD, ct0, rl, quad);
    __syncthreads();
    load_bf(hs1, bf, rl, quad);

    // L2: hidden of residual-2
    mfma_layerT<2>(w6 + 2 * 16384, bf, ct0, lane, acc);
    store_stripT<2>(hs0, acc, conv_b + 2 * H, ct0, rl, quad);
    __syncthreads();
    load_bf(hs0, bf, rl, quad);

    // L3: t += mlp_out;  z = t * s2s
    mfma_layerT<2>(w6 + 3 * 16384, bf, ct0, lane, acc);
#pragma unroll
    for (int ctl = 0; ctl < 2; ++ctl) {
        const int c = (ct0 + ctl) * 16 + quad * 4;
        float4 bb = *(const float4*)(conv_b + 3 * H + c);
        tD[ctl][0] = (tD[ctl][0] + silu_f(acc[ctl][0] + bb.x)) * svr[ctl].x;
        tD[ctl][1] = (tD[ctl][1] + silu_f(acc[ctl][1] + bb.y)) * svr[ctl].y;
        tD[ctl][2] = (tD[ctl][2] + silu_f(acc[ctl][2] + bb.z)) * svr[ctl].z;
        tD[ctl][3] = (tD[ctl][3] + silu_f(acc[ctl][3] + bb.w)) * svr[ctl].w;
    }
    store_strip_rawT<2>(hs1, tD, ct0, rl, quad);
    __syncthreads();
    load_bf(hs1, bf, rl, quad);

    // L4: hidden of final residual
    mfma_layerT<2>(w6 + 4 * 16384, bf, ct0, lane, acc);
    store_stripT<2>(hs0, acc, out_b, ct0, rl, quad);
    __syncthreads();
    load_bf(hs0, bf, rl, quad);

    // L5: out = z + mlp_out
    mfma_layerT<2>(w6 + 5 * 16384, bf, ct0, lane, acc);
#pragma unroll
    for (int ctl = 0; ctl < 2; ++ctl) {
        const int c = (ct0 + ctl) * 16 + quad * 4;
        float4 bb = *(const float4*)(out_b + H + c);
        float4 v;
        v.x = tD[ctl][0] + silu_f(acc[ctl][0] + bb.x);
        v.y = tD[ctl][1] + silu_f(acc[ctl][1] + bb.y);
        v.z = tD[ctl][2] + silu_f(acc[ctl][2] + bb.z);
        v.w = tD[ctl][3] + silu_f(acc[ctl][3] + bb.w);
        *(float4*)(y + rbase + c) = v;
    }
}

// ---------------------------------------------------------------------------
// Gather-reduce v6: ew in 32 NAMED f32x2 registers (not an array — arrays get
// demoted to per-edge reloads); 1-edge-ahead software pipeline for ef + sdst.
// 1 wave per node, lane covers h = {2l, 2l+1}.
// ---------------------------------------------------------------------------
#define EWLD(i) f32x2 w##i = *(const f32x2*)(ew + (i) * H + (lane << 1))
#define EMAC(q, a, b, c, d)                     \
    p0 += (f32x2){q.x, q.x} * a;                \
    p1 += (f32x2){q.y, q.y} * b;                \
    p2 += (f32x2){q.z, q.z} * c;                \
    p3 += (f32x2){q.w, q.w} * d;

__global__ __launch_bounds__(256, 3)
void conv_k(const float* __restrict__ ef, const float* __restrict__ sdst,
            const float* __restrict__ ew, const float* __restrict__ C,
            const int* __restrict__ offs, const int2* __restrict__ meta,
            float* __restrict__ conv)
{
    const int lane = threadIdx.x & 63;
    const int nid  = blockIdx.x * 4 + (threadIdx.x >> 6);   // 10000 blocks

    EWLD(0);  EWLD(1);  EWLD(2);  EWLD(3);  EWLD(4);  EWLD(5);  EWLD(6);  EWLD(7);
    EWLD(8);  EWLD(9);  EWLD(10); EWLD(11); EWLD(12); EWLD(13); EWLD(14); EWLD(15);
    EWLD(16); EWLD(17); EWLD(18); EWLD(19); EWLD(20); EWLD(21); EWLD(22); EWLD(23);
    EWLD(24); EWLD(25); EWLD(26); EWLD(27); EWLD(28); EWLD(29); EWLD(30); EWLD(31);

    const int start = offs[nid], end = offs[nid + 1];
    f32x2 acc = {0.f, 0.f};
    for (int base = start; base < end; base += 64) {
        const int cnt = min(64, end - base);
        int2 md = make_int2(0, 0);
        if (lane < cnt) md = meta[base + lane];

        // prime pipeline: edge 0
        int e  = __builtin_amdgcn_readlane(md.x, 0);
        int sc = __builtin_amdgcn_readlane(md.y, 0);
        f32x2 g = *(const f32x2*)(sdst + (size_t)sc * H + (lane << 1));
        const float4* ep = (const float4*)(ef + (size_t)e * 32);
        float4 q0 = ep[0], q1 = ep[1], q2 = ep[2], q3 = ep[3];
        float4 q4 = ep[4], q5 = ep[5], q6 = ep[6], q7 = ep[7];

        for (int j = 0; j < cnt; ++j) {
            f32x2 gn = {0.f, 0.f};
            float4 n0, n1, n2, n3, n4, n5, n6, n7;
            const bool more = (j + 1 < cnt);
            if (more) {
                const int en  = __builtin_amdgcn_readlane(md.x, j + 1);
                const int scn = __builtin_amdgcn_readlane(md.y, j + 1);
                gn = *(const f32x2*)(sdst + (size_t)scn * H + (lane << 1));
                const float4* np = (const float4*)(ef + (size_t)en * 32);
                n0 = np[0]; n1 = np[1]; n2 = np[2]; n3 = np[3];
                n4 = np[4]; n5 = np[5]; n6 = np[6]; n7 = np[7];
            }
            f32x2 p0 = {0.f, 0.f}, p1 = {0.f, 0.f};
            f32x2 p2 = {0.f, 0.f}, p3 = {0.f, 0.f};
            EMAC(q0, w0,  w1,  w2,  w3);
            EMAC(q1, w4,  w5,  w6,  w7);
            EMAC(q2, w8,  w9,  w10, w11);
            EMAC(q3, w12, w13, w14, w15);
            EMAC(q4, w16, w17, w18, w19);
            EMAC(q5, w20, w21, w22, w23);
            EMAC(q6, w24, w25, w26, w27);
            EMAC(q7, w28, w29, w30, w31);
            acc += g * ((p0 + p1) + (p2 + p3));
            if (more) {
                g = gn;
                q0 = n0; q1 = n1; q2 = n2; q3 = n3;
                q4 = n4; q5 = n5; q6 = n6; q7 = n7;
            }
        }
    }
    const float Cb = C[(unsigned)nid / 10000u];
    f32x2 st = acc * Cb;
    *(f32x2*)(conv + (size_t)nid * H + (lane << 1)) = st;
}

// ---------------------------------------------------------------------------
extern "C" void kernel_launch(void* const* d_in, const int* in_sizes, int n_in,
                              void* d_out, int out_size, void* d_ws, size_t ws_size,
                              hipStream_t stream)
{
    const float* scalar = (const float*)d_in[0];
    const float* ef     = (const float*)d_in[1];
    const int*   eidx   = (const int*)d_in[2];
    const float* C      = (const float*)d_in[3];
    const float* emb_w  = (const float*)d_in[4];
    const float* emb_b  = (const float*)d_in[5];
    const float* e_w    = (const float*)d_in[6];
    const float* conv_w = (const float*)d_in[7];
    const float* conv_b = (const float*)d_in[8];
    const float* out_w  = (const float*)d_in[9];
    const float* out_b  = (const float*)d_in[10];

    const int M = 40000;
    const size_t nodeElems = (size_t)M * H;            // 5,120,000

    float* s2s  = (float*)d_ws;
    float* sdst = s2s + nodeElems;
    float* conv = sdst + nodeElems;
    _Float16* wpk = (_Float16*)(conv + nodeElems);     // 163840 halves
    int* cnt    = (int*)(wpk + 163840);                // 40960
    int* offs   = cnt + 40960;                         // 40961 (+pad)
    int* cursor = offs + 40964;                        // 40960
    int2* meta  = (int2*)(cursor + 40960);             // 640000 int2

    dim3 blk(256);

    hipMemsetAsync(cnt, 0, 40960 * sizeof(int), stream);
    prep_k<<<2500, blk, 0, stream>>>(eidx, cnt, emb_w, conv_w, out_w, wpk);
    scan_k<<<1, 1024, 0, stream>>>(cnt, offs, cursor);
    scat_emb_k<<<5000, blk, 0, stream>>>(eidx, cursor, meta,
                                         scalar, wpk, emb_b, s2s, sdst);
    conv_k<<<10000, blk, 0, stream>>>(ef, sdst, e_w, C, offs, meta, conv);
    out6_k<<<2500, blk, 0, stream>>>(conv, s2s, wpk + 4 * 16384,
                                     conv_b, out_b, (float*)d_out);
}